// Round 18
// baseline (99.778 us; speedup 1.0000x reference)
//
#include <hip/hip_runtime.h>
#include <hip/hip_bf16.h>

#define C_   32
#define K_   16
#define DLLM 768
#define DM   256
#define H_   8
#define DK   32
#define G_   256
#define BL   4096
#define NN   4096
#define E_   768
#define LDP  4160          // P / VWt row stride: 4096 + 32 bias-fold + 32 zero pad
#define TEMPF 0.17677669529663687f
#define SCL2  0.2550348647f   // TEMP * log2(e)

typedef __attribute__((ext_vector_type(8))) short bf16x8;
typedef __attribute__((ext_vector_type(4))) float f32x4;
typedef unsigned int u32;

__device__ __forceinline__ unsigned short f2bf(float f) {
    unsigned int u = __float_as_uint(f);
    unsigned int r = (u + 0x7fffu + ((u >> 16) & 1u)) >> 16;
    return (unsigned short)r;
}
__device__ __forceinline__ float bf2f(unsigned int u) {
    return __uint_as_float(u << 16);
}

// async global -> LDS, 16 bytes per lane (wave-uniform LDS base + lane*16)
__device__ __forceinline__ void gl16(const void* g, void* l) {
    __builtin_amdgcn_global_load_lds(
        (const __attribute__((address_space(1))) u32*)g,
        (__attribute__((address_space(3))) u32*)l, 16, 0, 0);
}

// ---------------------------------------------------------------- K01: merged k1(MFMA kk/vv) + k0(cvt/bias-fold) + probsT
__global__ __launch_bounds__(256) void k01(const float* __restrict__ topk,
                                           const float* __restrict__ kp,
                                           const float* __restrict__ vp,
                                           float* __restrict__ kk,
                                           float* __restrict__ vv,
                                           const float* __restrict__ ts,
                                           const float* __restrict__ probs,
                                           const float* __restrict__ outb,
                                           unsigned short* __restrict__ tsb,
                                           unsigned short* __restrict__ P,
                                           unsigned short* __restrict__ VWt,
                                           float* __restrict__ probsT) {
    const int bid = blockIdx.x, t = threadIdx.x;
    __shared__ unsigned short a_lds[16 * 776];

    if (bid < 256) {                               // ---- k1: kk/vv via MFMA
        const int cl  = bid & 31;
        const int nq  = (bid >> 5) & 3;
        const int mat = bid >> 7;
        const float* src = mat ? vp : kp;
        float* dst       = mat ? vv : kk;

        const int lane = t & 63, w = t >> 6;
        const int c15 = lane & 15, gg = lane >> 4;

#pragma unroll
        for (int i = 0; i < 12; ++i) {
            const int e = (i * 256 + t) * 4;
            const int r = e / 768, d = e - r * 768;
            float4 v4 = *reinterpret_cast<const float4*>(topk + (size_t)cl * 12288 + e);
            unsigned u0, u1;
            asm("v_cvt_pk_bf16_f32 %0, %1, %2" : "=v"(u0) : "v"(v4.x), "v"(v4.y));
            asm("v_cvt_pk_bf16_f32 %0, %1, %2" : "=v"(u1) : "v"(v4.z), "v"(v4.w));
            uint2 p; p.x = u0; p.y = u1;
            *reinterpret_cast<uint2*>(&a_lds[r * 776 + d]) = p;
        }
        __syncthreads();

        const int gcol = nq * 64 + w * 16 + c15;
        const float* bp = src + (size_t)(cl * G_ + gcol) * (DLLM + 1);
        const float bias = bp[DLLM];

        f32x4 acc = {};
        float4 b0 = *reinterpret_cast<const float4*>(bp + gg * 8);
        float4 b1 = *reinterpret_cast<const float4*>(bp + gg * 8 + 4);
#pragma unroll
        for (int s = 0; s < 24; ++s) {
            float4 n0, n1;
            if (s < 23) {
                n0 = *reinterpret_cast<const float4*>(bp + (s + 1) * 32 + gg * 8);
                n1 = *reinterpret_cast<const float4*>(bp + (s + 1) * 32 + gg * 8 + 4);
            }
            union { unsigned u[4]; bf16x8 v; } bb;
            asm("v_cvt_pk_bf16_f32 %0, %1, %2" : "=v"(bb.u[0]) : "v"(b0.x), "v"(b0.y));
            asm("v_cvt_pk_bf16_f32 %0, %1, %2" : "=v"(bb.u[1]) : "v"(b0.z), "v"(b0.w));
            asm("v_cvt_pk_bf16_f32 %0, %1, %2" : "=v"(bb.u[2]) : "v"(b1.x), "v"(b1.y));
            asm("v_cvt_pk_bf16_f32 %0, %1, %2" : "=v"(bb.u[3]) : "v"(b1.z), "v"(b1.w));
            bf16x8 af = *reinterpret_cast<const bf16x8*>(&a_lds[c15 * 776 + s * 32 + gg * 8]);
            acc = __builtin_amdgcn_mfma_f32_16x16x32_bf16(af, bb.v, acc, 0, 0, 0);
            b0 = n0; b1 = n1;
        }
#pragma unroll
        for (int i = 0; i < 4; ++i) {
            const int row = gg * 4 + i;
            dst[(size_t)(cl * K_ + row) * G_ + gcol] = acc[i] + bias;
        }
    } else if (bid < 1280) {                       // ---- ts -> bf16
        const int idx = (bid - 256) * 1024 + t * 4;
        float4 v = *reinterpret_cast<const float4*>(ts + idx);
        uint2 o;
        o.x = f2bf(v.x) | ((unsigned)f2bf(v.y) << 16);
        o.y = f2bf(v.z) | ((unsigned)f2bf(v.w) << 16);
        *reinterpret_cast<uint2*>(tsb + idx) = o;
    } else if (bid < 1312) {                       // ---- P bias-fold + zero pad
        const int b2 = bid - 1280;
        const int row = b2 * 128 + (t >> 1);
        const int ch = (t & 1) * 16;
        unsigned short o[16];
#pragma unroll
        for (int j = 0; j < 16; ++j) o[j] = f2bf(probs[row * 32 + ch + j]);
        uint4 u0, u1;
        u0.x = o[0] | (o[1] << 16);  u0.y = o[2] | (o[3] << 16);
        u0.z = o[4] | (o[5] << 16);  u0.w = o[6] | (o[7] << 16);
        u1.x = o[8] | (o[9] << 16);  u1.y = o[10] | (o[11] << 16);
        u1.z = o[12] | (o[13] << 16); u1.w = o[14] | (o[15] << 16);
        unsigned short* dst = P + (size_t)row * LDP + 4096 + ch;
        *reinterpret_cast<uint4*>(dst) = u0;
        *reinterpret_cast<uint4*>(dst + 8) = u1;
        uint4 z = {0u, 0u, 0u, 0u};
        unsigned short* pz = P + (size_t)row * LDP + 4128 + ch;
        *reinterpret_cast<uint4*>(pz) = z;
        *reinterpret_cast<uint4*>(pz + 8) = z;
    } else if (bid < 1408) {                       // ---- VWt bias-fold
        const int idx = (bid - 1312) * 256 + t;    // 768*32 = 24576
        const int e = idx >> 5, cc = idx & 31;
        VWt[(size_t)e * LDP + 4096 + cc] = f2bf(outb[cc * E_ + e]);
        VWt[(size_t)e * LDP + 4128 + cc] = 0;
    } else {                                       // ---- probsT transpose (32 blocks x 128 rows)
        float* tl = reinterpret_cast<float*>(a_lds);   // [128][33]
        const int bl0p = (bid - 1408) * 128;
#pragma unroll
        for (int i = 0; i < 16; ++i) {
            const int row = i * 8 + (t >> 5);
            const int cc = t & 31;
            tl[row * 33 + cc] = probs[(size_t)(bl0p + row) * C_ + cc];
        }
        __syncthreads();
#pragma unroll
        for (int j = 0; j < 16; ++j) {
            const int cc = j * 2 + (t >> 7);
            const int bl = t & 127;
            probsT[(size_t)cc * BL + bl0p + bl] = tl[bl * 33 + cc];
        }
    }
}

// ---------------------------------------------------------------- K23: (merged) A2t + VWt builders
__global__ __launch_bounds__(768) void k23(const float* __restrict__ qp,
                                           const float* __restrict__ kk,
                                           const float* __restrict__ ow,
                                           const float* __restrict__ vv,
                                           unsigned short* __restrict__ A2t,
                                           float* __restrict__ abias,
                                           unsigned short* __restrict__ VWt) {
    const int c = blockIdx.x, h = blockIdx.y;
    const int t = threadIdx.x;
    __shared__ float kk_l[K_][DK];
    __shared__ float v_l[K_][DK];
    __shared__ float bq_l[DK];
    if (t < 512) {
        int k = t / DK, d = t % DK;
        kk_l[k][d] = kk[(size_t)(c * K_ + k) * G_ + h * DK + d];
        v_l[k][d]  = vv[(size_t)(c * K_ + k) * G_ + h * DK + d];
    }
    if (t < DK)
        bq_l[t] = qp[(size_t)(c * G_ + h * DK + t) * (DM + 1) + DM];
    __syncthreads();
    const int ch = c * H_ + h;
    {   // k3: VWt[e][n]
        const int e = t;
        float acc[K_];
#pragma unroll
        for (int k = 0; k < K_; ++k) acc[k] = 0.f;
        for (int d = 0; d < DK; ++d) {
            float w = ow[((size_t)ch * DK + d) * E_ + e];
#pragma unroll
            for (int k = 0; k < K_; ++k) acc[k] += w * v_l[k][d];
        }
#pragma unroll
        for (int k = 0; k < K_; ++k)
            VWt[(size_t)e * LDP + ch * 16 + k] = f2bf(acc[k]);
    }
    if (t < 256) {  // k2: A2t[n][m] (pre-scaled), abias
        const int m = t;
        float acc[K_];
#pragma unroll
        for (int k = 0; k < K_; ++k) acc[k] = 0.f;
        for (int d = 0; d < DK; ++d) {
            float wq = qp[(size_t)(c * G_ + h * DK + d) * (DM + 1) + m];
#pragma unroll
            for (int k = 0; k < K_; ++k) acc[k] += wq * kk_l[k][d];
        }
#pragma unroll
        for (int k = 0; k < K_; ++k)
            A2t[(size_t)(ch * 16 + k) * DM + m] = f2bf(acc[k] * SCL2);
        if (m < K_) {
            float s = 0.f;
#pragma unroll
            for (int d = 0; d < DK; ++d) s += bq_l[d] * kk_l[m][d];
            abias[ch * 16 + m] = s * SCL2;
        }
    }
}

// ---------------------------------------------------------------- K4: MFMA logits + exp2-softmax + prob scale -> P bf16
// BM(n)=128 x BN(bl)=128, BK=32; 2-buffer depth-1 counted vmcnt; 1024 blocks = 4/CU
__global__ __launch_bounds__(256, 4) void k4_att(const unsigned short* __restrict__ A2t,
                                                 const unsigned short* __restrict__ tsb,
                                                 const float* __restrict__ abias,
                                                 const float* __restrict__ probsT,
                                                 unsigned short* __restrict__ P) {
    const int n0  = blockIdx.x * 128;
    const int bl0 = blockIdx.y * 128;
    const int t = threadIdx.x;
    const int lane = t & 63, w = t >> 6;
    const int wr = w >> 1, wc = w & 1;
    const int c = lane & 15, g = lane >> 4;
    const int rsl = (c >> 1) & 3;

    __shared__ unsigned short a_l[2][128 * 32];
    __shared__ unsigned short b_l[2][128 * 32];
    __shared__ float ab_l[128];
    __shared__ float pb_l[128];

    if (t < 128) ab_l[t] = abias[n0 + t];
    else         pb_l[t - 128] = probsT[(size_t)(n0 >> 7) * BL + bl0 + (t - 128)];

    const int srow = t >> 2;
    const int sw = ((t & 3) ^ ((t >> 3) & 3)) * 8;

#define K4_STAGE(buf, kt)                                                         \
    {                                                                             \
        const int col_ = (kt) * 32 + sw;                                          \
        _Pragma("unroll")                                                         \
        for (int j = 0; j < 2; ++j)                                               \
            gl16(A2t + (size_t)(n0 + j * 64 + srow) * DM + col_,                  \
                 &a_l[buf][j * 2048 + t * 8]);                                    \
        _Pragma("unroll")                                                         \
        for (int j = 0; j < 2; ++j)                                               \
            gl16(tsb + (size_t)(bl0 + j * 64 + srow) * DM + col_,                 \
                 &b_l[buf][j * 2048 + t * 8]);                                    \
    }

    K4_STAGE(0, 0)
    asm volatile("s_waitcnt lgkmcnt(0)" ::: "memory");

    f32x4 acc[4][4] = {};

#pragma unroll
    for (int kt = 0; kt < 8; ++kt) {
        const int bcur = kt & 1;
        if (kt < 7) {
            K4_STAGE(bcur ^ 1, kt + 1)
            asm volatile("s_waitcnt vmcnt(4)" ::: "memory");
        } else {
            asm volatile("s_waitcnt vmcnt(0)" ::: "memory");
        }
        asm volatile("s_barrier" ::: "memory");
        bf16x8 af[4], bfr[4];
#pragma unroll
        for (int a = 0; a < 4; ++a)
            af[a] = *reinterpret_cast<const bf16x8*>(
                &a_l[bcur][(wr * 64 + a * 16 + c) * 32 + (g ^ rsl) * 8]);
#pragma unroll
        for (int b = 0; b < 4; ++b)
            bfr[b] = *reinterpret_cast<const bf16x8*>(
                &b_l[bcur][(wc * 64 + b * 16 + c) * 32 + (g ^ rsl) * 8]);
#pragma unroll
        for (int a = 0; a < 4; ++a)
#pragma unroll
            for (int b = 0; b < 4; ++b)
                acc[a][b] = __builtin_amdgcn_mfma_f32_16x16x32_bf16(af[a], bfr[b], acc[a][b], 0, 0, 0);
        if (kt < 7)
            asm volatile("s_barrier" ::: "memory");
    }
#undef K4_STAGE

#pragma unroll
    for (int a = 0; a < 4; ++a) {
        const int nbase = wr * 64 + a * 16 + g * 4;
#pragma unroll
        for (int b = 0; b < 4; ++b) {
            const int bll = wc * 64 + b * 16 + c;
            float e0 = __builtin_amdgcn_exp2f(acc[a][b][0] + ab_l[nbase + 0]);
            float e1 = __builtin_amdgcn_exp2f(acc[a][b][1] + ab_l[nbase + 1]);
            float e2 = __builtin_amdgcn_exp2f(acc[a][b][2] + ab_l[nbase + 2]);
            float e3 = __builtin_amdgcn_exp2f(acc[a][b][3] + ab_l[nbase + 3]);
            float s = (e0 + e1) + (e2 + e3);
            s += __shfl_xor(s, 16);
            s += __shfl_xor(s, 32);
            const float pv = pb_l[bll] * __builtin_amdgcn_rcpf(s);
            unsigned r0, r1;
            float p0 = e0 * pv, p1 = e1 * pv, p2 = e2 * pv, p3 = e3 * pv;
            asm("v_cvt_pk_bf16_f32 %0, %1, %2" : "=v"(r0) : "v"(p0), "v"(p1));
            asm("v_cvt_pk_bf16_f32 %0, %1, %2" : "=v"(r1) : "v"(p2), "v"(p3));
            uint2 o; o.x = r0; o.y = r1;
            *reinterpret_cast<uint2*>(P + (size_t)(bl0 + bll) * LDP + n0 + nbase) = o;
        }
    }
}

// ---------------------------------------------------------------- K5: part[ks] = P(K-sixth) @ VWt^T  (bf16 partials)
// 512 threads, 8 waves (2x4), wave tile 64x48, acc[4][3]; BM=128, BN=192, BK=32;
// 2-buffer depth-1 counted vmcnt (per-wave load count 3 or 2); split-K=6, 768 blocks
__global__ __launch_bounds__(512, 4) void k5_out(const unsigned short* __restrict__ P,
                                                 const unsigned short* __restrict__ VWt,
                                                 unsigned short* __restrict__ part) {
    const int wg = blockIdx.x;                     // 0..767
    const int xcd = wg & 7;
    const int local = wg >> 3;                     // 0..95 = 4 bl x 4 e x 6 ks
    const int bl0 = (xcd * 4 + (local & 3)) * 128;
    const int e0  = ((local >> 2) & 3) * 192;
    const int ks  = local >> 4;                    // 0..5

    const int t = threadIdx.x;
    const int lane = t & 63, w = t >> 6;           // 8 waves
    const int wr = w >> 2, wc = w & 3;             // 2 x 4 grid
    const int c = lane & 15, g = lane >> 4;
    const int rsl = (c >> 1) & 3;

    __shared__ unsigned short a_l[2][128 * 32];    // 2 x 8 KB
    __shared__ unsigned short b_l[2][192 * 32];    // 2 x 12 KB

    const int nstart = ks * 704;                   // 22 steps x 32; last gets 20
    const int nsteps = (ks == 5) ? 20 : 22;

    const int srow = t >> 2;                       // 0..127
    const int sw = ((t & 3) ^ ((t >> 3) & 3)) * 8;

    // A: 1 gl16 (rows 0..127); B: 1 gl16 rows 0..127 + 1 gl16 rows 128..191 (t<256 only)
#define K5_STAGE(buf, kt)                                                         \
    {                                                                             \
        const int col_ = nstart + (kt) * 32 + sw;                                 \
        gl16(P + (size_t)(bl0 + srow) * LDP + col_, &a_l[buf][t * 8]);            \
        gl16(VWt + (size_t)(e0 + srow) * LDP + col_, &b_l[buf][t * 8]);           \
        if (t < 256)                                                              \
            gl16(VWt + (size_t)(e0 + 128 + srow) * LDP + col_,                    \
                 &b_l[buf][4096 + t * 8]);                                        \
    }

    K5_STAGE(0, 0)

    f32x4 acc[4][3] = {};
    for (int kt = 0; kt < nsteps; ++kt) {
        const int bcur = kt & 1;
        if (kt + 1 < nsteps) {
            K5_STAGE(bcur ^ 1, kt + 1)
            if (w < 4) { asm volatile("s_waitcnt vmcnt(3)" ::: "memory"); }
            else       { asm volatile("s_waitcnt vmcnt(2)" ::: "memory"); }
        } else {
            asm volatile("s_waitcnt vmcnt(0)" ::: "memory");
        }
        asm volatile("s_barrier" ::: "memory");                 // PRE: tile kt visible to all
        bf16x8 af[4], bfr[3];
#pragma unroll
        for (int a = 0; a < 4; ++a)
            af[a] = *reinterpret_cast<const bf16x8*>(
                &a_l[bcur][(wr * 64 + a * 16 + c) * 32 + (g ^ rsl) * 8]);
#pragma unroll
        for (int b = 0; b < 3; ++b)
            bfr[b] = *reinterpret_cast<const bf16x8*>(
                &b_l[bcur][(wc * 48 + b * 16 + c) * 32 + (g ^ rsl) * 8]);
#pragma unroll
        for (int a = 0; a < 4; ++a)
#pragma unroll
            for (int b = 0; b < 3; ++b)
                acc[a][b] = __builtin_amdgcn_mfma_f32_16x16x32_bf16(af[a], bfr[b], acc[a][b], 0, 0, 0);
        if (kt + 1 < nsteps)
            asm volatile("s_barrier" ::: "memory");             // POST: buf safe to overwrite
    }
#undef K5_STAGE

    unsigned short* pp = part + ((size_t)ks * BL + bl0) * E_ + e0;
#pragma unroll
    for (int a = 0; a < 4; ++a)
#pragma unroll
        for (int b = 0; b < 3; ++b)
#pragma unroll
            for (int i = 0; i < 4; ++i)
                pp[(size_t)(wr * 64 + a * 16 + g * 4 + i) * E_ + wc * 48 + b * 16 + c] =
                    f2bf(acc[a][b][i]);
}

// ---------------------------------------------------------------- k6: out = sum of 6 bf16 partials
__global__ __launch_bounds__(256) void k6_red(const unsigned short* __restrict__ part,
                                              float* __restrict__ out) {
    const size_t base = ((size_t)blockIdx.x * 256 + threadIdx.x) * 8;
    float s[8] = {};
#pragma unroll
    for (int ks = 0; ks < 6; ++ks) {
        uint4 v = *reinterpret_cast<const uint4*>(part + (size_t)ks * (BL * E_) + base);
        const unsigned u[4] = {v.x, v.y, v.z, v.w};
#pragma unroll
        for (int j = 0; j < 4; ++j) {
            s[2 * j]     += bf2f(u[j] & 0xffffu);
            s[2 * j + 1] += bf2f(u[j] >> 16);
        }
    }
    *reinterpret_cast<float4*>(out + base)     = make_float4(s[0], s[1], s[2], s[3]);
    *reinterpret_cast<float4*>(out + base + 4) = make_float4(s[4], s[5], s[6], s[7]);
}

// ----------------------------------------------------------------
extern "C" void kernel_launch(void* const* d_in, const int* in_sizes, int n_in,
                              void* d_out, int out_size, void* d_ws, size_t ws_size,
                              hipStream_t stream) {
    const float* topk  = (const float*)d_in[0];
    const float* ts    = (const float*)d_in[1];
    const float* probs = (const float*)d_in[2];
    const float* qp    = (const float*)d_in[3];
    const float* kp    = (const float*)d_in[4];
    const float* vp    = (const float*)d_in[5];
    const float* ow    = (const float*)d_in[6];
    const float* ob    = (const float*)d_in[7];
    float* out = (float*)d_out;

    char* wp = (char*)d_ws;
    float* kk            = (float*)wp;           wp += 524288;
    float* vv            = (float*)wp;           wp += 524288;
    float* ab            = (float*)wp;           wp += 16384;
    float* probsT        = (float*)wp;           wp += 524288;
    unsigned short* tsb  = (unsigned short*)wp;  wp += 2097152;
    unsigned short* A2t  = (unsigned short*)wp;  wp += 2097152;
    unsigned short* VWt  = (unsigned short*)wp;  wp += (size_t)E_ * LDP * 2;   // 6,389,760
    unsigned short* P    = (unsigned short*)wp;  wp += (size_t)BL * LDP * 2;   // 34,078,720
    unsigned short* part = (unsigned short*)wp;  // 6 * 4096*768*2 = 37,748,736

    k01   <<<1440,         256, 0, stream>>>(topk, kp, vp, kk, vv,
                                             ts, probs, ob, tsb, P, VWt, probsT);
    k23   <<<dim3(32, 8),  768, 0, stream>>>(qp, kk, ow, vv, A2t, ab, VWt);
    k4_att<<<dim3(32, 32), 256, 0, stream>>>(A2t, tsb, ab, probsT, P);
    k5_out<<<768,          512, 0, stream>>>(P, VWt, part);
    k6_red<<<1536,         256, 0, stream>>>(part, out);
}

// Round 19
// 95.146 us; speedup vs baseline: 1.0487x; 1.0487x over previous
//
#include <hip/hip_runtime.h>
#include <hip/hip_bf16.h>

#define C_   32
#define K_   16
#define DLLM 768
#define DM   256
#define H_   8
#define DK   32
#define G_   256
#define BL   4096
#define NN   4096
#define E_   768
#define LDP  4160          // P / VWt row stride: 4096 + 32 bias-fold + 32 zero pad
#define TEMPF 0.17677669529663687f
#define SCL2  0.2550348647f   // TEMP * log2(e)

typedef __attribute__((ext_vector_type(8))) short bf16x8;
typedef __attribute__((ext_vector_type(4))) float f32x4;
typedef unsigned int u32;

__device__ __forceinline__ unsigned short f2bf(float f) {
    unsigned int u = __float_as_uint(f);
    unsigned int r = (u + 0x7fffu + ((u >> 16) & 1u)) >> 16;
    return (unsigned short)r;
}
__device__ __forceinline__ float bf2f(unsigned int u) {
    return __uint_as_float(u << 16);
}

// async global -> LDS, 16 bytes per lane (wave-uniform LDS base + lane*16)
__device__ __forceinline__ void gl16(const void* g, void* l) {
    __builtin_amdgcn_global_load_lds(
        (const __attribute__((address_space(1))) u32*)g,
        (__attribute__((address_space(3))) u32*)l, 16, 0, 0);
}

// ---------------------------------------------------------------- K01: merged k1(MFMA kk/vv) + k0(cvt/bias-fold) + probsT
__global__ __launch_bounds__(256) void k01(const float* __restrict__ topk,
                                           const float* __restrict__ kp,
                                           const float* __restrict__ vp,
                                           float* __restrict__ kk,
                                           float* __restrict__ vv,
                                           const float* __restrict__ ts,
                                           const float* __restrict__ probs,
                                           const float* __restrict__ outb,
                                           unsigned short* __restrict__ tsb,
                                           unsigned short* __restrict__ P,
                                           unsigned short* __restrict__ VWt,
                                           float* __restrict__ probsT) {
    const int bid = blockIdx.x, t = threadIdx.x;
    __shared__ unsigned short a_lds[16 * 776];

    if (bid < 256) {                               // ---- k1: kk/vv via MFMA
        const int cl  = bid & 31;
        const int nq  = (bid >> 5) & 3;
        const int mat = bid >> 7;
        const float* src = mat ? vp : kp;
        float* dst       = mat ? vv : kk;

        const int lane = t & 63, w = t >> 6;
        const int c15 = lane & 15, gg = lane >> 4;

#pragma unroll
        for (int i = 0; i < 12; ++i) {
            const int e = (i * 256 + t) * 4;
            const int r = e / 768, d = e - r * 768;
            float4 v4 = *reinterpret_cast<const float4*>(topk + (size_t)cl * 12288 + e);
            unsigned u0, u1;
            asm("v_cvt_pk_bf16_f32 %0, %1, %2" : "=v"(u0) : "v"(v4.x), "v"(v4.y));
            asm("v_cvt_pk_bf16_f32 %0, %1, %2" : "=v"(u1) : "v"(v4.z), "v"(v4.w));
            uint2 p; p.x = u0; p.y = u1;
            *reinterpret_cast<uint2*>(&a_lds[r * 776 + d]) = p;
        }
        __syncthreads();

        const int gcol = nq * 64 + w * 16 + c15;
        const float* bp = src + (size_t)(cl * G_ + gcol) * (DLLM + 1);
        const float bias = bp[DLLM];

        f32x4 acc = {};
        float4 b0 = *reinterpret_cast<const float4*>(bp + gg * 8);
        float4 b1 = *reinterpret_cast<const float4*>(bp + gg * 8 + 4);
#pragma unroll
        for (int s = 0; s < 24; ++s) {
            float4 n0, n1;
            if (s < 23) {
                n0 = *reinterpret_cast<const float4*>(bp + (s + 1) * 32 + gg * 8);
                n1 = *reinterpret_cast<const float4*>(bp + (s + 1) * 32 + gg * 8 + 4);
            }
            union { unsigned u[4]; bf16x8 v; } bb;
            asm("v_cvt_pk_bf16_f32 %0, %1, %2" : "=v"(bb.u[0]) : "v"(b0.x), "v"(b0.y));
            asm("v_cvt_pk_bf16_f32 %0, %1, %2" : "=v"(bb.u[1]) : "v"(b0.z), "v"(b0.w));
            asm("v_cvt_pk_bf16_f32 %0, %1, %2" : "=v"(bb.u[2]) : "v"(b1.x), "v"(b1.y));
            asm("v_cvt_pk_bf16_f32 %0, %1, %2" : "=v"(bb.u[3]) : "v"(b1.z), "v"(b1.w));
            bf16x8 af = *reinterpret_cast<const bf16x8*>(&a_lds[c15 * 776 + s * 32 + gg * 8]);
            acc = __builtin_amdgcn_mfma_f32_16x16x32_bf16(af, bb.v, acc, 0, 0, 0);
            b0 = n0; b1 = n1;
        }
#pragma unroll
        for (int i = 0; i < 4; ++i) {
            const int row = gg * 4 + i;
            dst[(size_t)(cl * K_ + row) * G_ + gcol] = acc[i] + bias;
        }
    } else if (bid < 1280) {                       // ---- ts -> bf16
        const int idx = (bid - 256) * 1024 + t * 4;
        float4 v = *reinterpret_cast<const float4*>(ts + idx);
        uint2 o;
        o.x = f2bf(v.x) | ((unsigned)f2bf(v.y) << 16);
        o.y = f2bf(v.z) | ((unsigned)f2bf(v.w) << 16);
        *reinterpret_cast<uint2*>(tsb + idx) = o;
    } else if (bid < 1312) {                       // ---- P bias-fold + zero pad
        const int b2 = bid - 1280;
        const int row = b2 * 128 + (t >> 1);
        const int ch = (t & 1) * 16;
        unsigned short o[16];
#pragma unroll
        for (int j = 0; j < 16; ++j) o[j] = f2bf(probs[row * 32 + ch + j]);
        uint4 u0, u1;
        u0.x = o[0] | (o[1] << 16);  u0.y = o[2] | (o[3] << 16);
        u0.z = o[4] | (o[5] << 16);  u0.w = o[6] | (o[7] << 16);
        u1.x = o[8] | (o[9] << 16);  u1.y = o[10] | (o[11] << 16);
        u1.z = o[12] | (o[13] << 16); u1.w = o[14] | (o[15] << 16);
        unsigned short* dst = P + (size_t)row * LDP + 4096 + ch;
        *reinterpret_cast<uint4*>(dst) = u0;
        *reinterpret_cast<uint4*>(dst + 8) = u1;
        uint4 z = {0u, 0u, 0u, 0u};
        unsigned short* pz = P + (size_t)row * LDP + 4128 + ch;
        *reinterpret_cast<uint4*>(pz) = z;
        *reinterpret_cast<uint4*>(pz + 8) = z;
    } else if (bid < 1408) {                       // ---- VWt bias-fold
        const int idx = (bid - 1312) * 256 + t;    // 768*32 = 24576
        const int e = idx >> 5, cc = idx & 31;
        VWt[(size_t)e * LDP + 4096 + cc] = f2bf(outb[cc * E_ + e]);
        VWt[(size_t)e * LDP + 4128 + cc] = 0;
    } else {                                       // ---- probsT transpose (32 blocks x 128 rows)
        float* tl = reinterpret_cast<float*>(a_lds);   // [128][33]
        const int bl0p = (bid - 1408) * 128;
#pragma unroll
        for (int i = 0; i < 16; ++i) {
            const int row = i * 8 + (t >> 5);
            const int cc = t & 31;
            tl[row * 33 + cc] = probs[(size_t)(bl0p + row) * C_ + cc];
        }
        __syncthreads();
#pragma unroll
        for (int j = 0; j < 16; ++j) {
            const int cc = j * 2 + (t >> 7);
            const int bl = t & 127;
            probsT[(size_t)cc * BL + bl0p + bl] = tl[bl * 33 + cc];
        }
    }
}

// ---------------------------------------------------------------- K23: (merged) A2t + VWt builders
__global__ __launch_bounds__(768) void k23(const float* __restrict__ qp,
                                           const float* __restrict__ kk,
                                           const float* __restrict__ ow,
                                           const float* __restrict__ vv,
                                           unsigned short* __restrict__ A2t,
                                           float* __restrict__ abias,
                                           unsigned short* __restrict__ VWt) {
    const int c = blockIdx.x, h = blockIdx.y;
    const int t = threadIdx.x;
    __shared__ float kk_l[K_][DK];
    __shared__ float v_l[K_][DK];
    __shared__ float bq_l[DK];
    if (t < 512) {
        int k = t / DK, d = t % DK;
        kk_l[k][d] = kk[(size_t)(c * K_ + k) * G_ + h * DK + d];
        v_l[k][d]  = vv[(size_t)(c * K_ + k) * G_ + h * DK + d];
    }
    if (t < DK)
        bq_l[t] = qp[(size_t)(c * G_ + h * DK + t) * (DM + 1) + DM];
    __syncthreads();
    const int ch = c * H_ + h;
    {   // k3: VWt[e][n]
        const int e = t;
        float acc[K_];
#pragma unroll
        for (int k = 0; k < K_; ++k) acc[k] = 0.f;
        for (int d = 0; d < DK; ++d) {
            float w = ow[((size_t)ch * DK + d) * E_ + e];
#pragma unroll
            for (int k = 0; k < K_; ++k) acc[k] += w * v_l[k][d];
        }
#pragma unroll
        for (int k = 0; k < K_; ++k)
            VWt[(size_t)e * LDP + ch * 16 + k] = f2bf(acc[k]);
    }
    if (t < 256) {  // k2: A2t[n][m] (pre-scaled), abias
        const int m = t;
        float acc[K_];
#pragma unroll
        for (int k = 0; k < K_; ++k) acc[k] = 0.f;
        for (int d = 0; d < DK; ++d) {
            float wq = qp[(size_t)(c * G_ + h * DK + d) * (DM + 1) + m];
#pragma unroll
            for (int k = 0; k < K_; ++k) acc[k] += wq * kk_l[k][d];
        }
#pragma unroll
        for (int k = 0; k < K_; ++k)
            A2t[(size_t)(ch * 16 + k) * DM + m] = f2bf(acc[k] * SCL2);
        if (m < K_) {
            float s = 0.f;
#pragma unroll
            for (int d = 0; d < DK; ++d) s += bq_l[d] * kk_l[m][d];
            abias[ch * 16 + m] = s * SCL2;
        }
    }
}

// ---------------------------------------------------------------- K4: MFMA logits + exp2-softmax + prob scale -> P bf16
// BM(n)=128 x BN(bl)=128, BK=32; 2-buffer depth-1 counted vmcnt; 1024 blocks = 4/CU
__global__ __launch_bounds__(256, 4) void k4_att(const unsigned short* __restrict__ A2t,
                                                 const unsigned short* __restrict__ tsb,
                                                 const float* __restrict__ abias,
                                                 const float* __restrict__ probsT,
                                                 unsigned short* __restrict__ P) {
    const int n0  = blockIdx.x * 128;
    const int bl0 = blockIdx.y * 128;
    const int t = threadIdx.x;
    const int lane = t & 63, w = t >> 6;
    const int wr = w >> 1, wc = w & 1;
    const int c = lane & 15, g = lane >> 4;
    const int rsl = (c >> 1) & 3;

    __shared__ unsigned short a_l[2][128 * 32];
    __shared__ unsigned short b_l[2][128 * 32];
    __shared__ float ab_l[128];
    __shared__ float pb_l[128];

    if (t < 128) ab_l[t] = abias[n0 + t];
    else         pb_l[t - 128] = probsT[(size_t)(n0 >> 7) * BL + bl0 + (t - 128)];

    const int srow = t >> 2;
    const int sw = ((t & 3) ^ ((t >> 3) & 3)) * 8;

#define K4_STAGE(buf, kt)                                                         \
    {                                                                             \
        const int col_ = (kt) * 32 + sw;                                          \
        _Pragma("unroll")                                                         \
        for (int j = 0; j < 2; ++j)                                               \
            gl16(A2t + (size_t)(n0 + j * 64 + srow) * DM + col_,                  \
                 &a_l[buf][j * 2048 + t * 8]);                                    \
        _Pragma("unroll")                                                         \
        for (int j = 0; j < 2; ++j)                                               \
            gl16(tsb + (size_t)(bl0 + j * 64 + srow) * DM + col_,                 \
                 &b_l[buf][j * 2048 + t * 8]);                                    \
    }

    K4_STAGE(0, 0)
    asm volatile("s_waitcnt lgkmcnt(0)" ::: "memory");

    f32x4 acc[4][4] = {};

#pragma unroll
    for (int kt = 0; kt < 8; ++kt) {
        const int bcur = kt & 1;
        if (kt < 7) {
            K4_STAGE(bcur ^ 1, kt + 1)
            asm volatile("s_waitcnt vmcnt(4)" ::: "memory");
        } else {
            asm volatile("s_waitcnt vmcnt(0)" ::: "memory");
        }
        asm volatile("s_barrier" ::: "memory");
        bf16x8 af[4], bfr[4];
#pragma unroll
        for (int a = 0; a < 4; ++a)
            af[a] = *reinterpret_cast<const bf16x8*>(
                &a_l[bcur][(wr * 64 + a * 16 + c) * 32 + (g ^ rsl) * 8]);
#pragma unroll
        for (int b = 0; b < 4; ++b)
            bfr[b] = *reinterpret_cast<const bf16x8*>(
                &b_l[bcur][(wc * 64 + b * 16 + c) * 32 + (g ^ rsl) * 8]);
#pragma unroll
        for (int a = 0; a < 4; ++a)
#pragma unroll
            for (int b = 0; b < 4; ++b)
                acc[a][b] = __builtin_amdgcn_mfma_f32_16x16x32_bf16(af[a], bfr[b], acc[a][b], 0, 0, 0);
        if (kt < 7)
            asm volatile("s_barrier" ::: "memory");
    }
#undef K4_STAGE

#pragma unroll
    for (int a = 0; a < 4; ++a) {
        const int nbase = wr * 64 + a * 16 + g * 4;
#pragma unroll
        for (int b = 0; b < 4; ++b) {
            const int bll = wc * 64 + b * 16 + c;
            float e0 = __builtin_amdgcn_exp2f(acc[a][b][0] + ab_l[nbase + 0]);
            float e1 = __builtin_amdgcn_exp2f(acc[a][b][1] + ab_l[nbase + 1]);
            float e2 = __builtin_amdgcn_exp2f(acc[a][b][2] + ab_l[nbase + 2]);
            float e3 = __builtin_amdgcn_exp2f(acc[a][b][3] + ab_l[nbase + 3]);
            float s = (e0 + e1) + (e2 + e3);
            s += __shfl_xor(s, 16);
            s += __shfl_xor(s, 32);
            const float pv = pb_l[bll] * __builtin_amdgcn_rcpf(s);
            unsigned r0, r1;
            float p0 = e0 * pv, p1 = e1 * pv, p2 = e2 * pv, p3 = e3 * pv;
            asm("v_cvt_pk_bf16_f32 %0, %1, %2" : "=v"(r0) : "v"(p0), "v"(p1));
            asm("v_cvt_pk_bf16_f32 %0, %1, %2" : "=v"(r1) : "v"(p2), "v"(p3));
            uint2 o; o.x = r0; o.y = r1;
            *reinterpret_cast<uint2*>(P + (size_t)(bl0 + bll) * LDP + n0 + nbase) = o;
        }
    }
}

// ---------------------------------------------------------------- K5: part[ks] = P(K-sixth) @ VWt^T  (bf16 partials)
// BM=128, BN=192, BK=32; 2-buffer depth-1 counted vmcnt; split-K=6 -> 768 blocks (round-17 known-good)
__global__ __launch_bounds__(256, 3) void k5_out(const unsigned short* __restrict__ P,
                                                 const unsigned short* __restrict__ VWt,
                                                 unsigned short* __restrict__ part) {
    const int wg = blockIdx.x;                     // 0..767
    const int xcd = wg & 7;
    const int local = wg >> 3;                     // 0..95 = 4 bl x 4 e x 6 ks
    const int bl0 = (xcd * 4 + (local & 3)) * 128;
    const int e0  = ((local >> 2) & 3) * 192;
    const int ks  = local >> 4;                    // 0..5

    const int t = threadIdx.x;
    const int lane = t & 63, w = t >> 6;
    const int wr = w >> 1, wc = w & 1;
    const int c = lane & 15, g = lane >> 4;
    const int rsl = (c >> 1) & 3;

    __shared__ unsigned short a_l[2][128 * 32];    // 2 x 8 KB
    __shared__ unsigned short b_l[2][192 * 32];    // 2 x 12 KB

    const int nstart = ks * 704;                   // 22 steps x 32; last gets 20
    const int nsteps = (ks == 5) ? 20 : 22;

    const int srow = t >> 2;
    const int sw = ((t & 3) ^ ((t >> 3) & 3)) * 8;

#define K5_STAGE(buf, kt)                                                         \
    {                                                                             \
        const int col_ = nstart + (kt) * 32 + sw;                                 \
        _Pragma("unroll")                                                         \
        for (int j = 0; j < 2; ++j)                                               \
            gl16(P + (size_t)(bl0 + j * 64 + srow) * LDP + col_,                  \
                 &a_l[buf][j * 2048 + t * 8]);                                    \
        _Pragma("unroll")                                                         \
        for (int j = 0; j < 3; ++j)                                               \
            gl16(VWt + (size_t)(e0 + j * 64 + srow) * LDP + col_,                 \
                 &b_l[buf][j * 2048 + t * 8]);                                    \
    }

    K5_STAGE(0, 0)

    f32x4 acc[4][6] = {};
    for (int kt = 0; kt < nsteps; ++kt) {
        const int bcur = kt & 1;
        if (kt + 1 < nsteps) {
            K5_STAGE(bcur ^ 1, kt + 1)
            asm volatile("s_waitcnt vmcnt(5)" ::: "memory");    // tile kt arrived (mine)
        } else {
            asm volatile("s_waitcnt vmcnt(0)" ::: "memory");
        }
        asm volatile("s_barrier" ::: "memory");                 // PRE: tile kt visible to all
        bf16x8 af[4], bfr[6];
#pragma unroll
        for (int a = 0; a < 4; ++a)
            af[a] = *reinterpret_cast<const bf16x8*>(
                &a_l[bcur][(wr * 64 + a * 16 + c) * 32 + (g ^ rsl) * 8]);
#pragma unroll
        for (int b = 0; b < 6; ++b)
            bfr[b] = *reinterpret_cast<const bf16x8*>(
                &b_l[bcur][(wc * 96 + b * 16 + c) * 32 + (g ^ rsl) * 8]);
#pragma unroll
        for (int a = 0; a < 4; ++a)
#pragma unroll
            for (int b = 0; b < 6; ++b)
                acc[a][b] = __builtin_amdgcn_mfma_f32_16x16x32_bf16(af[a], bfr[b], acc[a][b], 0, 0, 0);
        if (kt + 1 < nsteps)
            asm volatile("s_barrier" ::: "memory");             // POST: buf safe to overwrite
    }
#undef K5_STAGE

    unsigned short* pp = part + ((size_t)ks * BL + bl0) * E_ + e0;
#pragma unroll
    for (int a = 0; a < 4; ++a)
#pragma unroll
        for (int b = 0; b < 6; ++b)
#pragma unroll
            for (int i = 0; i < 4; ++i)
                pp[(size_t)(wr * 64 + a * 16 + g * 4 + i) * E_ + wc * 96 + b * 16 + c] =
                    f2bf(acc[a][b][i]);
}

// ---------------------------------------------------------------- k6: out = sum of 6 bf16 partials
__global__ __launch_bounds__(256) void k6_red(const unsigned short* __restrict__ part,
                                              float* __restrict__ out) {
    const size_t base = ((size_t)blockIdx.x * 256 + threadIdx.x) * 8;
    float s[8] = {};
#pragma unroll
    for (int ks = 0; ks < 6; ++ks) {
        uint4 v = *reinterpret_cast<const uint4*>(part + (size_t)ks * (BL * E_) + base);
        const unsigned u[4] = {v.x, v.y, v.z, v.w};
#pragma unroll
        for (int j = 0; j < 4; ++j) {
            s[2 * j]     += bf2f(u[j] & 0xffffu);
            s[2 * j + 1] += bf2f(u[j] >> 16);
        }
    }
    *reinterpret_cast<float4*>(out + base)     = make_float4(s[0], s[1], s[2], s[3]);
    *reinterpret_cast<float4*>(out + base + 4) = make_float4(s[4], s[5], s[6], s[7]);
}

// ----------------------------------------------------------------
extern "C" void kernel_launch(void* const* d_in, const int* in_sizes, int n_in,
                              void* d_out, int out_size, void* d_ws, size_t ws_size,
                              hipStream_t stream) {
    const float* topk  = (const float*)d_in[0];
    const float* ts    = (const float*)d_in[1];
    const float* probs = (const float*)d_in[2];
    const float* qp    = (const float*)d_in[3];
    const float* kp    = (const float*)d_in[4];
    const float* vp    = (const float*)d_in[5];
    const float* ow    = (const float*)d_in[6];
    const float* ob    = (const float*)d_in[7];
    float* out = (float*)d_out;

    char* wp = (char*)d_ws;
    float* kk            = (float*)wp;           wp += 524288;
    float* vv            = (float*)wp;           wp += 524288;
    float* ab            = (float*)wp;           wp += 16384;
    float* probsT        = (float*)wp;           wp += 524288;
    unsigned short* tsb  = (unsigned short*)wp;  wp += 2097152;
    unsigned short* A2t  = (unsigned short*)wp;  wp += 2097152;
    unsigned short* VWt  = (unsigned short*)wp;  wp += (size_t)E_ * LDP * 2;   // 6,389,760
    unsigned short* P    = (unsigned short*)wp;  wp += (size_t)BL * LDP * 2;   // 34,078,720
    unsigned short* part = (unsigned short*)wp;  // 6 * 4096*768*2 = 37,748,736

    k01   <<<1440,         256, 0, stream>>>(topk, kp, vp, kk, vv,
                                             ts, probs, ob, tsb, P, VWt, probsT);
    k23   <<<dim3(32, 8),  768, 0, stream>>>(qp, kk, ow, vv, A2t, ab, VWt);
    k4_att<<<dim3(32, 32), 256, 0, stream>>>(A2t, tsb, ab, probsT, P);
    k5_out<<<768,          256, 0, stream>>>(P, VWt, part);
    k6_red<<<1536,         256, 0, stream>>>(part, out);
}